// Round 4
// baseline (118.057 us; speedup 1.0000x reference)
//
#include <hip/hip_runtime.h>

// IntLayerNorm (quantized), D=1024. One wave per row, 4 rows per wave:
// w/b quantized ONCE into registers (32 VGPRs) and reused across rows,
// cutting per-row loads from 12 float4 to 4 and amortizing w/b cvt.
// Memory-bound: 64MB read + 64MB write -> target ~6.2 TB/s.

constexpr int Dn   = 1024;
constexpr int QD   = 16;   // Q_D
constexpr int INVD = 64;   // round(2^16 / 1024)
constexpr int QLUT = 15;
constexpr int RPW  = 4;    // rows per wave
// Q_W = 8 -> scale 256, output divide 1/256

__global__ __launch_bounds__(256) void intln_kernel(
    const float* __restrict__ x,
    const float* __restrict__ w,
    const float* __restrict__ b,
    const int* __restrict__ lut,         // 32 x int32
    float* __restrict__ out,
    int nrows)
{
    const int lane = threadIdx.x & 63;
    const int wid  = threadIdx.x >> 6;            // 0..3
    const int gw   = blockIdx.x * 4 + wid;        // global wave id
    const int row0 = gw * RPW;
    if (row0 >= nrows) return;
    const int coff = lane * 4;                    // within-chunk column offset

    // ---- quantize w/b once per wave (rows share them) ----
    int wq[16], bq[16];
#pragma unroll
    for (int c = 0; c < 4; ++c) {
        const float4 wv = *reinterpret_cast<const float4*>(w + c * 256 + coff);
        const float4 bv = *reinterpret_cast<const float4*>(b + c * 256 + coff);
        wq[c*4+0] = __float2int_rn(wv.x * 256.0f);
        wq[c*4+1] = __float2int_rn(wv.y * 256.0f);
        wq[c*4+2] = __float2int_rn(wv.z * 256.0f);
        wq[c*4+3] = __float2int_rn(wv.w * 256.0f);
        bq[c*4+0] = __float2int_rn(bv.x * 256.0f);
        bq[c*4+1] = __float2int_rn(bv.y * 256.0f);
        bq[c*4+2] = __float2int_rn(bv.z * 256.0f);
        bq[c*4+3] = __float2int_rn(bv.w * 256.0f);
    }

#pragma unroll
    for (int r = 0; r < RPW; ++r) {
        const size_t rbase = (size_t)(row0 + r) * Dn;

        // ---- load x: 4 coalesced float4 chunks (1KB/wave/instr) ----
        float4 xv[4];
#pragma unroll
        for (int c = 0; c < 4; ++c)
            xv[c] = *reinterpret_cast<const float4*>(x + rbase + c * 256 + coff);

        int xi[16];
#pragma unroll
        for (int c = 0; c < 4; ++c) {
            xi[c*4+0] = __float2int_rn(xv[c].x);
            xi[c*4+1] = __float2int_rn(xv[c].y);
            xi[c*4+2] = __float2int_rn(xv[c].z);
            xi[c*4+3] = __float2int_rn(xv[c].w);
        }

        int s = 0, ss = 0;                        // per-lane partials fit int32
#pragma unroll
        for (int j = 0; j < 16; ++j) { s += xi[j]; ss += xi[j] * xi[j]; }

        // ---- wave butterfly reduce (int32) ----
#pragma unroll
        for (int off = 32; off; off >>= 1) {
            s  += __shfl_xor(s,  off, 64);
            ss += __shfl_xor(ss, off, 64);
        }

        // ---- uniform per-row tail: int64, bit-exact vs reference ----
        const long long S  = s;
        const long long SS = ss;
        const long long mean64 = (S * INVD) >> QD;
        const long long sum_sq = SS - 2 * mean64 * S + (long long)Dn * mean64 * mean64;
        long long var = (sum_sq * INVD) >> QD;
        if (var < 1) var = 1;

        const int k  = 63 - __clzll((unsigned long long)var);   // floor(log2(var))
        const int sa = k - 4;                                   // M = 4
        const int mant = (sa >= 0) ? (int)((var >> sa) & 15)
                                   : (int)((var << (-sa)) & 15);
        const int idx = ((k & 1) << 4) | mant;
        const int inv = lut[idx];                               // uniform addr
        const int tot = (k >> 1) + QLUT;                        // p + SHIFT(0) + Q_LUT
        const int mean = (int)mean64;

        // ---- per-element: y*inv (int32), one 32x32->64 widening mul, shift ----
        float ov[16];
#pragma unroll
        for (int j = 0; j < 16; ++j) {
            const int yi = xi[j] - mean;
            const int t  = yi * inv;                  // |yi|*2^15 < 2^31
            const long long prod = (long long)t * wq[j];
            ov[j] = (float)((int)(prod >> tot) + bq[j]) * 0.00390625f;
        }

#pragma unroll
        for (int c = 0; c < 4; ++c) {
            float4 o = { ov[c*4+0], ov[c*4+1], ov[c*4+2], ov[c*4+3] };
            *reinterpret_cast<float4*>(out + rbase + c * 256 + coff) = o;
        }
    }
}

extern "C" void kernel_launch(void* const* d_in, const int* in_sizes, int n_in,
                              void* d_out, int out_size, void* d_ws, size_t ws_size,
                              hipStream_t stream) {
    const float* x   = (const float*)d_in[0];
    const float* w   = (const float*)d_in[1];
    const float* b   = (const float*)d_in[2];
    const int*   lut = (const int*)d_in[3];
    float* out = (float*)d_out;

    const int nrows  = in_sizes[0] / Dn;               // 8*2048 = 16384
    const int blocks = (nrows + 4 * RPW - 1) / (4 * RPW);  // 4 waves/block, RPW rows/wave
    intln_kernel<<<blocks, 256, 0, stream>>>(x, w, b, lut, out, nrows);
}